// Round 3
// baseline (3745.890 us; speedup 1.0000x reference)
//
#include <hip/hip_runtime.h>
#include <math.h>

typedef _Float16 f16;
typedef _Float16 f16x8 __attribute__((ext_vector_type(8)));
typedef float f32x4 __attribute__((ext_vector_type(4)));

#define TOK 1024   // B*S
#define DM  512
#define SEQ 512
#define NB  2
#define CHUNK 32
#define NCH (SEQ/CHUNK)   // 16

// ---------------- embedding gather (writes f16) ----------------
__global__ __launch_bounds__(256) void embed_gather(
    const int* __restrict__ x,
    const float* __restrict__ t0, const float* __restrict__ t1,
    const float* __restrict__ t2, const float* __restrict__ t3,
    const float* __restrict__ t4, const float* __restrict__ t5,
    f16* __restrict__ E) {
  int t = blockIdx.x;
  int tid = threadIdx.x;
  const int* xb = x + t * 6;
  for (int c = tid; c < 1216; c += 256) {
    float val;
    if (c < 128)       val = t0[xb[0]*128 + c]        * 11.313708498984761f;
    else if (c < 384)  val = t1[xb[1]*256 + (c-128)]  * 16.0f;
    else if (c < 448)  val = t2[xb[2]*64  + (c-384)]  * 8.0f;
    else if (c < 960)  val = t3[xb[3]*512 + (c-448)]  * 22.627416997969522f;
    else if (c < 1088) val = t4[xb[4]*128 + (c-960)]  * 11.313708498984761f;
    else               val = t5[xb[5]*128 + (c-1088)] * 11.313708498984761f;
    E[(size_t)t*1216 + c] = (f16)val;
  }
}

// ---------------- weight fp32 -> fp16 transpose-convert ----------------
__global__ __launch_bounds__(256) void transp_convert(
    const float* __restrict__ in, f16* __restrict__ out,
    int K, int N, size_t instride, size_t outstride) {
  int lz = blockIdx.z;
  const float* I = in + (size_t)lz * instride;
  f16* O = out + (size_t)lz * outstride;
  __shared__ float tile[32][33];
  int k0 = blockIdx.x * 32, n0 = blockIdx.y * 32;
  int tid = threadIdx.x;
  int cr = tid >> 5, cc = tid & 31;
#pragma unroll
  for (int p = 0; p < 4; ++p)
    tile[cr + p*8][cc] = I[(size_t)(k0 + cr + p*8) * N + n0 + cc];
  __syncthreads();
#pragma unroll
  for (int p = 0; p < 4; ++p)
    O[(size_t)(n0 + cr + p*8) * K + k0 + cc] = (f16)tile[cc][cr + p*8];
}

// combined Wq/Wk/Wv/Wo conversion: z = layer*4 + which
__global__ __launch_bounds__(256) void transp_convert_qkvo(
    const float* __restrict__ Wq, const float* __restrict__ Wk,
    const float* __restrict__ Wv, const float* __restrict__ Wo,
    f16* __restrict__ qkvw, f16* __restrict__ wot) {
  int z = blockIdx.z;
  int lz = z >> 2, m = z & 3;
  const float* I = ((m == 0) ? Wq : (m == 1) ? Wk : (m == 2) ? Wv : Wo)
                   + (size_t)lz * 262144;
  f16* O = (m < 3) ? qkvw + (size_t)lz * 786432 + (size_t)m * 262144
                   : wot + (size_t)lz * 262144;
  __shared__ float tile[32][33];
  int k0 = blockIdx.x * 32, n0 = blockIdx.y * 32;
  int tid = threadIdx.x;
  int cr = tid >> 5, cc = tid & 31;
#pragma unroll
  for (int p = 0; p < 4; ++p)
    tile[cr + p*8][cc] = I[(size_t)(k0 + cr + p*8) * 512 + n0 + cc];
  __syncthreads();
#pragma unroll
  for (int p = 0; p < 4; ++p)
    O[(size_t)(n0 + cr + p*8) * 512 + k0 + cc] = (f16)tile[cc][cr + p*8];
}

// ---------------- fp16 MFMA GEMM + fused epilogues ----------------
// C[M][N] = A[M][K] (f16) * Bt[N][K] (f16), fp32 accumulate.
// E=0: bias -> fp32 o0
// E=1: bias + exact gelu -> f16 (o0 cast)
// E=2: QKV fused: cols 0-511 -> o0 (+b0, elu+1), 512-1023 -> o1 (+b1, elu+1),
//      1024-1535 -> o2 (+b2); all fp32, row stride 512
// E=3: bias + positional encoding -> fp32 o0 AND f16 o1
template<int E>
__global__ __launch_bounds__(256) void mfma_gemm(
    const f16* __restrict__ A, const f16* __restrict__ Bt,
    const float* __restrict__ b0, const float* __restrict__ b1,
    const float* __restrict__ b2,
    float* __restrict__ o0, float* __restrict__ o1, float* __restrict__ o2,
    int M, int K, int N) {
  __shared__ f16 As[64][72];   // 64 k + 8 pad: 2-way-max aliasing on b128
  __shared__ f16 Bs[64][72];
  const int tid = threadIdx.x;
  const int m0 = blockIdx.x * 64, n0 = blockIdx.y * 64;
  const int w = tid >> 6, l = tid & 63;
  const int wr = w >> 1, wc = w & 1;
  const int g = l >> 4, r = l & 15;
  const int lr = tid >> 2, lc = (tid & 3) * 8;
  f32x4 acc[2][2] = {};
  const f16* Ap = A + (size_t)(m0 + lr) * K + lc;
  const f16* Bp = Bt + (size_t)(n0 + lr) * K + lc;
  for (int k0 = 0; k0 < K; k0 += 64) {
    *(f16x8*)&As[lr][lc]      = *(const f16x8*)(Ap + k0);
    *(f16x8*)&As[lr][lc + 32] = *(const f16x8*)(Ap + k0 + 32);
    *(f16x8*)&Bs[lr][lc]      = *(const f16x8*)(Bp + k0);
    *(f16x8*)&Bs[lr][lc + 32] = *(const f16x8*)(Bp + k0 + 32);
    __syncthreads();
#pragma unroll
    for (int kk = 0; kk < 2; ++kk) {
      f16x8 a0  = *(const f16x8*)&As[wr*32 + r][kk*32 + g*8];
      f16x8 a1  = *(const f16x8*)&As[wr*32 + 16 + r][kk*32 + g*8];
      f16x8 bv0 = *(const f16x8*)&Bs[wc*32 + r][kk*32 + g*8];
      f16x8 bv1 = *(const f16x8*)&Bs[wc*32 + 16 + r][kk*32 + g*8];
      acc[0][0] = __builtin_amdgcn_mfma_f32_16x16x32_f16(a0, bv0, acc[0][0], 0, 0, 0);
      acc[0][1] = __builtin_amdgcn_mfma_f32_16x16x32_f16(a0, bv1, acc[0][1], 0, 0, 0);
      acc[1][0] = __builtin_amdgcn_mfma_f32_16x16x32_f16(a1, bv0, acc[1][0], 0, 0, 0);
      acc[1][1] = __builtin_amdgcn_mfma_f32_16x16x32_f16(a1, bv1, acc[1][1], 0, 0, 0);
    }
    __syncthreads();
  }
#pragma unroll
  for (int m = 0; m < 2; ++m) {
    int row = m0 + wr*32 + m*16 + g*4;
#pragma unroll
    for (int n = 0; n < 2; ++n) {
      int col = n0 + wc*32 + n*16 + r;
      float pediv = 0.0f;
      if (E == 3) pediv = __expf((float)(col >> 1) * (-0.035977892070386504f));
#pragma unroll
      for (int i = 0; i < 4; ++i) {
        float v = acc[m][n][i];
        if (E == 2) {
          int which = col >> 9;
          int lc2 = col & 511;
          const float* bb = (which == 0) ? b0 : (which == 1) ? b1 : b2;
          float* oo = (which == 0) ? o0 : (which == 1) ? o1 : o2;
          v += bb[lc2];
          if (which < 2) v = (v > 0.0f) ? v + 1.0f : __expf(v);
          oo[(size_t)(row + i) * 512 + lc2] = v;
        } else if (E == 1) {
          v += b0[col];
          v = 0.5f * v * (1.0f + erff(v * 0.70710678118654752f));
          ((f16*)o0)[(size_t)(row + i) * N + col] = (f16)v;
        } else if (E == 3) {
          v += b0[col];
          float ang = (float)((row + i) & (SEQ-1)) * pediv;
          v += (col & 1) ? cosf(ang) : sinf(ang);
          o0[(size_t)(row + i) * N + col] = v;
          ((f16*)o1)[(size_t)(row + i) * N + col] = (f16)v;
        } else {
          v += b0[col];
          o0[(size_t)(row + i) * N + col] = v;
        }
      }
    }
  }
}

// ---------------- attention: fused chunk-sums + exclusive prefix scan ----------------
// grid 16 (b*8+h); KV prefix state lives in registers (16 f32/thread)
__global__ __launch_bounds__(256) void attn_kv_scan(
    const float* __restrict__ Kg, const float* __restrict__ Vg,
    float* __restrict__ kvst, float* __restrict__ ksum) {
  int bh = blockIdx.x;
  int b = bh >> 3, h = bh & 7;
  __shared__ float Ks[CHUNK][64], Vs[CHUNK][64];
  int tid = threadIdx.x;
  int d = tid >> 2, m0 = (tid & 3) * 16;
  float acc[16] = {};
  float kacc = 0.0f;
  for (int ch = 0; ch < NCH; ++ch) {
    const float* Kbase = Kg + ((size_t)(b*SEQ + ch*CHUNK))*DM + h*64;
    const float* Vbase = Vg + ((size_t)(b*SEQ + ch*CHUNK))*DM + h*64;
    __syncthreads();
#pragma unroll
    for (int ld = 0; ld < CHUNK*64/256; ++ld) {
      int e = tid + ld*256;
      int rr = e >> 6, cc = e & 63;
      Ks[rr][cc] = Kbase[(size_t)rr*DM + cc];
      Vs[rr][cc] = Vbase[(size_t)rr*DM + cc];
    }
    __syncthreads();
    // write exclusive prefix for this chunk
    float* dst = kvst + (((size_t)(bh*NCH + ch)*64 + d)*64) + m0;
#pragma unroll
    for (int j = 0; j < 16; ++j) dst[j] = acc[j];
    if (tid < 64) ksum[(size_t)(bh*NCH + ch)*64 + tid] = kacc;
    // accumulate this chunk into the running state
    for (int s = 0; s < CHUNK; ++s) {
      float kd = Ks[s][d];
#pragma unroll
      for (int j = 0; j < 16; ++j) acc[j] += kd * Vs[s][m0+j];
    }
    if (tid < 64) {
      float ss = 0.0f;
      for (int rr = 0; rr < CHUNK; ++rr) ss += Ks[rr][tid];
      kacc += ss;
    }
  }
}

// ---------------- attention: per-chunk output (writes f16) ----------------
__global__ __launch_bounds__(256) void attn_chunk_out(
    const float* __restrict__ Qg, const float* __restrict__ Kg,
    const float* __restrict__ Vg, const float* __restrict__ kvst,
    const float* __restrict__ ksum, f16* __restrict__ O) {
  int ch = blockIdx.x, bh = blockIdx.y;
  int b = bh >> 3, h = bh & 7;
  __shared__ float Qs[CHUNK][64], Ks[CHUNK][64], Vs[CHUNK][64];
  __shared__ float kvp[64][64];
  __shared__ float Sl[CHUNK][CHUNK+1];
  __shared__ float ksp[64];
  __shared__ float den[CHUNK];
  int tid = threadIdx.x;
  const float* Qbase = Qg + ((size_t)(b*SEQ + ch*CHUNK))*DM + h*64;
  const float* Kbase = Kg + ((size_t)(b*SEQ + ch*CHUNK))*DM + h*64;
  const float* Vbase = Vg + ((size_t)(b*SEQ + ch*CHUNK))*DM + h*64;
#pragma unroll
  for (int ld = 0; ld < CHUNK*64/256; ++ld) {
    int e = tid + ld*256;
    int rr = e >> 6, cc = e & 63;
    Qs[rr][cc] = Qbase[(size_t)rr*DM + cc];
    Ks[rr][cc] = Kbase[(size_t)rr*DM + cc];
    Vs[rr][cc] = Vbase[(size_t)rr*DM + cc];
  }
  {
    const float* src = kvst + (size_t)(bh*NCH + ch)*4096;
#pragma unroll
    for (int ld = 0; ld < 16; ++ld) {
      int e = tid + ld*256;
      ((float*)kvp)[e] = src[e];
    }
  }
  if (tid < 64) ksp[tid] = ksum[(size_t)(bh*NCH + ch)*64 + tid];
  __syncthreads();
#pragma unroll
  for (int ld = 0; ld < 4; ++ld) {
    int e = tid + ld*256;
    int i = e >> 5, j = e & 31;
    float s = 0;
    for (int d2 = 0; d2 < 64; ++d2) s += Qs[i][d2] * Ks[j][d2];
    Sl[i][j] = s;
  }
  __syncthreads();
  if (tid < CHUNK) {
    int i = tid;
    float dsum = 0;
    for (int d2 = 0; d2 < 64; ++d2) dsum += Qs[i][d2] * ksp[d2];
    for (int j = 0; j <= i; ++j) dsum += Sl[i][j];
    den[i] = 1.0f / (dsum + 1e-6f);
  }
  __syncthreads();
  int row = tid >> 3, m0 = (tid & 7) * 8;
  float acc[8] = {};
  for (int d2 = 0; d2 < 64; ++d2) {
    float qd = Qs[row][d2];
#pragma unroll
    for (int j = 0; j < 8; ++j) acc[j] += qd * kvp[d2][m0+j];
  }
  for (int j2 = 0; j2 <= row; ++j2) {
    float sv = Sl[row][j2];
#pragma unroll
    for (int j = 0; j < 8; ++j) acc[j] += sv * Vs[j2][m0+j];
  }
  float zi = den[row];
  f16* dst = O + ((size_t)(b*SEQ + ch*CHUNK + row))*DM + h*64 + m0;
#pragma unroll
  for (int j = 0; j < 8; ++j) dst[j] = (f16)(acc[j] * zi);
}

// ---------------- residual + layernorm (dual fp32 + f16 output) ----------------
__global__ __launch_bounds__(256) void resid_ln(
    const float* __restrict__ x, const float* __restrict__ r,
    const float* __restrict__ g, const float* __restrict__ bb,
    float* __restrict__ out, f16* __restrict__ out16) {
  int t = blockIdx.x;
  int tid = threadIdx.x;
  __shared__ float red[256];
  const float* xb = x + (size_t)t*DM;
  float v0 = xb[tid];
  float v1 = xb[tid+256];
  if (r) {
    const float* rb = r + (size_t)t*DM;
    v0 += rb[tid];
    v1 += rb[tid+256];
  }
  red[tid] = v0 + v1;
  __syncthreads();
  for (int o = 128; o > 0; o >>= 1) {
    if (tid < o) red[tid] += red[tid+o];
    __syncthreads();
  }
  float mean = red[0] * (1.0f/512.0f);
  __syncthreads();
  float d0 = v0 - mean, d1 = v1 - mean;
  red[tid] = d0*d0 + d1*d1;
  __syncthreads();
  for (int o = 128; o > 0; o >>= 1) {
    if (tid < o) red[tid] += red[tid+o];
    __syncthreads();
  }
  float rs = rsqrtf(red[0] * (1.0f/512.0f) + 1e-5f);
  float r0 = d0*rs*g[tid]     + bb[tid];
  float r1 = d1*rs*g[tid+256] + bb[tid+256];
  out[(size_t)t*DM + tid]     = r0;
  out[(size_t)t*DM + tid+256] = r1;
  if (out16) {
    out16[(size_t)t*DM + tid]     = (f16)r0;
    out16[(size_t)t*DM + tid+256] = (f16)r1;
  }
}

// ---------------- collapsed output heads (parallel) ----------------
struct HeadPtrs {
  const float* pw[6]; const float* pb[6];
  const float* vw[6]; const float* vb[6];
};

__global__ __launch_bounds__(64) void head_u_par(HeadPtrs hp, float* __restrict__ U,
                                                 float* __restrict__ Cc) {
  const int vsz[6] = {56, 135, 18, 87, 18, 25};
  const int off[6] = {0, 56, 191, 209, 296, 314};
  int d = blockIdx.x;          // 0..511 -> U[d]; 512 -> Cc
  int tid = threadIdx.x;
  float acc = 0.0f;
  for (int jj = tid; jj < 339; jj += 64) {
    int i;
    if (jj < 191) i = (jj < 56) ? 0 : 1;
    else if (jj < 296) i = (jj < 209) ? 2 : 3;
    else i = (jj < 314) ? 4 : 5;
    int j = jj - off[i];
    float wv = (d < 512) ? hp.pw[i][(size_t)d * vsz[i] + j] : hp.pb[i][j];
    acc += wv * hp.vw[i][j];
  }
#pragma unroll
  for (int s = 32; s > 0; s >>= 1) acc += __shfl_down(acc, s);
  if (tid == 0) {
    if (d < 512) U[d] = acc;
    else {
      for (int i = 0; i < 6; ++i) acc += hp.vb[i][0];
      Cc[0] = acc;
    }
  }
}

__global__ __launch_bounds__(512) void final_out(
    const float* __restrict__ hf, const float* __restrict__ U,
    const float* __restrict__ Cc, float* __restrict__ out) {
  int b = blockIdx.x;
  int d = threadIdx.x;
  __shared__ float red[512];
  float cs = 0;
  const float* hb = hf + (size_t)b*SEQ*DM + d;
  for (int s = 0; s < SEQ; ++s) cs += hb[(size_t)s*DM];
  red[d] = cs * U[d];
  __syncthreads();
  for (int o = 256; o > 0; o >>= 1) {
    if (d < o) red[d] += red[d+o];
    __syncthreads();
  }
  if (d == 0) out[b] = (red[0] * (1.0f/512.0f) + Cc[0]) * (1.0f/6.0f);
}

// ---------------- launch ----------------
extern "C" void kernel_launch(void* const* d_in, const int* in_sizes, int n_in,
                              void* d_out, int out_size, void* d_ws, size_t ws_size,
                              hipStream_t stream) {
  const int*   x    = (const int*)d_in[0];
  const float* T0   = (const float*)d_in[1];
  const float* T1   = (const float*)d_in[2];
  const float* T2   = (const float*)d_in[3];
  const float* T3   = (const float*)d_in[4];
  const float* T4   = (const float*)d_in[5];
  const float* T5   = (const float*)d_in[6];
  const float* in_w = (const float*)d_in[7];
  const float* in_b = (const float*)d_in[8];
  const float* Wq   = (const float*)d_in[9];
  const float* Wk   = (const float*)d_in[10];
  const float* Wv   = (const float*)d_in[11];
  const float* Wo   = (const float*)d_in[12];
  const float* W1   = (const float*)d_in[13];
  const float* W2   = (const float*)d_in[14];
  const float* bq   = (const float*)d_in[15];
  const float* bk   = (const float*)d_in[16];
  const float* bv   = (const float*)d_in[17];
  const float* bo   = (const float*)d_in[18];
  const float* bf1  = (const float*)d_in[19];
  const float* bf2  = (const float*)d_in[20];
  const float* b1n  = (const float*)d_in[21];
  const float* b2n  = (const float*)d_in[22];
  const float* g1   = (const float*)d_in[23];
  const float* g2   = (const float*)d_in[24];
  const float* gf   = (const float*)d_in[25];
  const float* bfn  = (const float*)d_in[26];
  HeadPtrs hp;
  for (int i = 0; i < 6; ++i) {
    hp.pw[i] = (const float*)d_in[27 + i*4];
    hp.pb[i] = (const float*)d_in[28 + i*4];
    hp.vw[i] = (const float*)d_in[29 + i*4];
    hp.vb[i] = (const float*)d_in[30 + i*4];
  }

  float* ws   = (float*)d_ws;
  float* h    = ws;                 // 1024*512 fp32
  float* q    = h    + 524288;
  float* k    = q    + 524288;
  float* v    = k    + 524288;
  float* a2   = v    + 524288;
  float* h2   = a2   + 524288;
  float* y    = h2   + 524288;
  float* kvst = y    + 524288;      // 16*16*64*64
  float* ksum = kvst + 1048576;     // 16*16*64
  float* U    = ksum + 16384;
  float* Cc   = U    + 512;
  f16* E16    = (f16*)(Cc + 16);    // 1024*1216
  f16* hf16   = E16   + 1245184;    // 1024*512
  f16* h2f16  = hf16  + 524288;
  f16* attn16 = h2f16 + 524288;
  f16* ff16   = attn16+ 524288;     // 1024*2048
  f16* in_wt  = ff16  + 2097152;    // 512*1216
  f16* qkvw   = in_wt + 623616;     // 12*1536*512
  f16* wot    = qkvw  + 9437184;    // 12*512*512
  f16* w1t    = wot   + 3145728;    // 12*2048*512
  f16* w2t    = w1t   + 12582912;   // 12*512*2048

  // weight conversion
  transp_convert<<<dim3(38,16,1),  256, 0, stream>>>(in_w, in_wt, 1216, 512, 0, 0);
  transp_convert_qkvo<<<dim3(16,16,48), 256, 0, stream>>>(Wq, Wk, Wv, Wo, qkvw, wot);
  transp_convert<<<dim3(16,64,12), 256, 0, stream>>>(W1, w1t,  512, 2048, 1048576, 1048576);
  transp_convert<<<dim3(64,16,12), 256, 0, stream>>>(W2, w2t, 2048,  512, 1048576, 1048576);

  embed_gather<<<TOK, 256, 0, stream>>>(x, T0, T1, T2, T3, T4, T5, E16);
  // input GEMM + bias + positional encoding, dual fp32/f16 out
  mfma_gemm<3><<<dim3(16,8), 256, 0, stream>>>(E16, in_wt, in_b, nullptr, nullptr,
                                               h, (float*)hf16, nullptr, TOK, 1216, 512);

  for (int l = 0; l < 12; ++l) {
    mfma_gemm<2><<<dim3(16,24), 256, 0, stream>>>(hf16, qkvw + (size_t)l*786432,
        bq + l*512, bk + l*512, bv + l*512, q, k, v, TOK, 512, 1536);
    attn_kv_scan<<<16, 256, 0, stream>>>(k, v, kvst, ksum);
    attn_chunk_out<<<dim3(NCH,16), 256, 0, stream>>>(q, k, v, kvst, ksum, attn16);
    mfma_gemm<0><<<dim3(16,8), 256, 0, stream>>>(attn16, wot + (size_t)l*262144,
        bo + l*512, nullptr, nullptr, a2, nullptr, nullptr, TOK, 512, 512);
    resid_ln<<<TOK, 256, 0, stream>>>(h, a2, g1 + l*512, b1n + l*512, h2, h2f16);
    mfma_gemm<1><<<dim3(16,32), 256, 0, stream>>>(h2f16, w1t + (size_t)l*1048576,
        bf1 + l*2048, nullptr, nullptr, (float*)ff16, nullptr, nullptr, TOK, 512, 2048);
    mfma_gemm<0><<<dim3(16,8), 256, 0, stream>>>(ff16, w2t + (size_t)l*1048576,
        bf2 + l*512, nullptr, nullptr, y, nullptr, nullptr, TOK, 2048, 512);
    resid_ln<<<TOK, 256, 0, stream>>>(h2, y, g2 + l*512, b2n + l*512, h, hf16);
  }

  resid_ln<<<TOK, 256, 0, stream>>>(h, nullptr, gf, bfn, h2, nullptr);
  head_u_par<<<513, 64, 0, stream>>>(hp, U, Cc);
  final_out<<<NB, 512, 0, stream>>>(h2, U, Cc, (float*)d_out);
}

// Round 5
// 2328.610 us; speedup vs baseline: 1.6086x; 1.6086x over previous
//
#include <hip/hip_runtime.h>
#include <math.h>

typedef _Float16 f16;
typedef _Float16 f16x8 __attribute__((ext_vector_type(8)));
typedef float f32x4 __attribute__((ext_vector_type(4)));

#define TOK 1024   // B*S
#define DM  512
#define SEQ 512
#define NB  2
#define CHUNK 32
#define NCH (SEQ/CHUNK)   // 16

// ---------------- embedding gather (writes f16) ----------------
__global__ __launch_bounds__(256) void embed_gather(
    const int* __restrict__ x,
    const float* __restrict__ t0, const float* __restrict__ t1,
    const float* __restrict__ t2, const float* __restrict__ t3,
    const float* __restrict__ t4, const float* __restrict__ t5,
    f16* __restrict__ E) {
  int t = blockIdx.x;
  int tid = threadIdx.x;
  const int* xb = x + t * 6;
  for (int c = tid; c < 1216; c += 256) {
    float val;
    if (c < 128)       val = t0[xb[0]*128 + c]        * 11.313708498984761f;
    else if (c < 384)  val = t1[xb[1]*256 + (c-128)]  * 16.0f;
    else if (c < 448)  val = t2[xb[2]*64  + (c-384)]  * 8.0f;
    else if (c < 960)  val = t3[xb[3]*512 + (c-448)]  * 22.627416997969522f;
    else if (c < 1088) val = t4[xb[4]*128 + (c-960)]  * 11.313708498984761f;
    else               val = t5[xb[5]*128 + (c-1088)] * 11.313708498984761f;
    E[(size_t)t*1216 + c] = (f16)val;
  }
}

// ---------------- weight fp32 -> fp16 transpose-convert ----------------
__global__ __launch_bounds__(256) void transp_convert(
    const float* __restrict__ in, f16* __restrict__ out,
    int K, int N, size_t instride, size_t outstride) {
  int lz = blockIdx.z;
  const float* I = in + (size_t)lz * instride;
  f16* O = out + (size_t)lz * outstride;
  __shared__ float tile[32][33];
  int k0 = blockIdx.x * 32, n0 = blockIdx.y * 32;
  int tid = threadIdx.x;
  int cr = tid >> 5, cc = tid & 31;
#pragma unroll
  for (int p = 0; p < 4; ++p)
    tile[cr + p*8][cc] = I[(size_t)(k0 + cr + p*8) * N + n0 + cc];
  __syncthreads();
#pragma unroll
  for (int p = 0; p < 4; ++p)
    O[(size_t)(n0 + cr + p*8) * K + k0 + cc] = (f16)tile[cc][cr + p*8];
}

// combined Wq/Wk/Wv/Wo conversion: z = layer*4 + which
__global__ __launch_bounds__(256) void transp_convert_qkvo(
    const float* __restrict__ Wq, const float* __restrict__ Wk,
    const float* __restrict__ Wv, const float* __restrict__ Wo,
    f16* __restrict__ qkvw, f16* __restrict__ wot) {
  int z = blockIdx.z;
  int lz = z >> 2, m = z & 3;
  const float* I = ((m == 0) ? Wq : (m == 1) ? Wk : (m == 2) ? Wv : Wo)
                   + (size_t)lz * 262144;
  f16* O = (m < 3) ? qkvw + (size_t)lz * 786432 + (size_t)m * 262144
                   : wot + (size_t)lz * 262144;
  __shared__ float tile[32][33];
  int k0 = blockIdx.x * 32, n0 = blockIdx.y * 32;
  int tid = threadIdx.x;
  int cr = tid >> 5, cc = tid & 31;
#pragma unroll
  for (int p = 0; p < 4; ++p)
    tile[cr + p*8][cc] = I[(size_t)(k0 + cr + p*8) * 512 + n0 + cc];
  __syncthreads();
#pragma unroll
  for (int p = 0; p < 4; ++p)
    O[(size_t)(n0 + cr + p*8) * 512 + k0 + cc] = (f16)tile[cc][cr + p*8];
}

// ---------------- fp16 MFMA GEMM + fused epilogues ----------------
// C[M][N] = A[M][K] (f16) * Bt[N][K] (f16), fp32 accumulate.
// E=0: bias -> fp32 o0
// E=1: bias + exact gelu -> f16 (o0 cast)
// E=2: QKV fused: cols 0-511 -> o0 (+b0, elu+1), 512-1023 -> o1 (+b1, elu+1),
//      1024-1535 -> o2 (+b2); all fp32, row stride 512
// E=3: bias + positional encoding -> fp32 o0 AND f16 o1
template<int E>
__global__ __launch_bounds__(256) void mfma_gemm(
    const f16* __restrict__ A, const f16* __restrict__ Bt,
    const float* __restrict__ b0, const float* __restrict__ b1,
    const float* __restrict__ b2,
    float* __restrict__ o0, float* __restrict__ o1, float* __restrict__ o2,
    int M, int K, int N) {
  __shared__ f16 As[64][72];   // 64 k + 8 pad: 2-way-max aliasing on b128
  __shared__ f16 Bs[64][72];
  const int tid = threadIdx.x;
  const int m0 = blockIdx.x * 64, n0 = blockIdx.y * 64;
  const int w = tid >> 6, l = tid & 63;
  const int wr = w >> 1, wc = w & 1;
  const int g = l >> 4, r = l & 15;
  const int lr = tid >> 2, lc = (tid & 3) * 8;
  f32x4 acc[2][2] = {};
  const f16* Ap = A + (size_t)(m0 + lr) * K + lc;
  const f16* Bp = Bt + (size_t)(n0 + lr) * K + lc;
  for (int k0 = 0; k0 < K; k0 += 64) {
    *(f16x8*)&As[lr][lc]      = *(const f16x8*)(Ap + k0);
    *(f16x8*)&As[lr][lc + 32] = *(const f16x8*)(Ap + k0 + 32);
    *(f16x8*)&Bs[lr][lc]      = *(const f16x8*)(Bp + k0);
    *(f16x8*)&Bs[lr][lc + 32] = *(const f16x8*)(Bp + k0 + 32);
    __syncthreads();
#pragma unroll
    for (int kk = 0; kk < 2; ++kk) {
      f16x8 a0  = *(const f16x8*)&As[wr*32 + r][kk*32 + g*8];
      f16x8 a1  = *(const f16x8*)&As[wr*32 + 16 + r][kk*32 + g*8];
      f16x8 bv0 = *(const f16x8*)&Bs[wc*32 + r][kk*32 + g*8];
      f16x8 bv1 = *(const f16x8*)&Bs[wc*32 + 16 + r][kk*32 + g*8];
      acc[0][0] = __builtin_amdgcn_mfma_f32_16x16x32_f16(a0, bv0, acc[0][0], 0, 0, 0);
      acc[0][1] = __builtin_amdgcn_mfma_f32_16x16x32_f16(a0, bv1, acc[0][1], 0, 0, 0);
      acc[1][0] = __builtin_amdgcn_mfma_f32_16x16x32_f16(a1, bv0, acc[1][0], 0, 0, 0);
      acc[1][1] = __builtin_amdgcn_mfma_f32_16x16x32_f16(a1, bv1, acc[1][1], 0, 0, 0);
    }
    __syncthreads();
  }
#pragma unroll
  for (int m = 0; m < 2; ++m) {
    int row = m0 + wr*32 + m*16 + g*4;
#pragma unroll
    for (int n = 0; n < 2; ++n) {
      int col = n0 + wc*32 + n*16 + r;
      float pediv = 0.0f;
      if (E == 3) pediv = __expf((float)(col >> 1) * (-0.035977892070386504f));
#pragma unroll
      for (int i = 0; i < 4; ++i) {
        float v = acc[m][n][i];
        if (E == 2) {
          int which = col >> 9;
          int lc2 = col & 511;
          const float* bb = (which == 0) ? b0 : (which == 1) ? b1 : b2;
          float* oo = (which == 0) ? o0 : (which == 1) ? o1 : o2;
          v += bb[lc2];
          if (which < 2) v = (v > 0.0f) ? v + 1.0f : __expf(v);
          oo[(size_t)(row + i) * 512 + lc2] = v;
        } else if (E == 1) {
          v += b0[col];
          v = 0.5f * v * (1.0f + erff(v * 0.70710678118654752f));
          ((f16*)o0)[(size_t)(row + i) * N + col] = (f16)v;
        } else if (E == 3) {
          v += b0[col];
          float ang = (float)((row + i) & (SEQ-1)) * pediv;
          v += (col & 1) ? cosf(ang) : sinf(ang);
          o0[(size_t)(row + i) * N + col] = v;
          ((f16*)o1)[(size_t)(row + i) * N + col] = (f16)v;
        } else {
          v += b0[col];
          o0[(size_t)(row + i) * N + col] = v;
        }
      }
    }
  }
}

// ---------------- attention pass A: per-chunk KV / K sums (parallel) ----------------
__global__ __launch_bounds__(256) void attn_chunk_sums(
    const float* __restrict__ Kg, const float* __restrict__ Vg,
    float* __restrict__ kvst, float* __restrict__ ksum) {
  int ch = blockIdx.x, bh = blockIdx.y;
  int b = bh >> 3, h = bh & 7;
  __shared__ float Ks[CHUNK][64], Vs[CHUNK][64];
  int tid = threadIdx.x;
  const float* Kbase = Kg + ((size_t)(b*SEQ + ch*CHUNK))*DM + h*64;
  const float* Vbase = Vg + ((size_t)(b*SEQ + ch*CHUNK))*DM + h*64;
#pragma unroll
  for (int l = 0; l < CHUNK*64/256; ++l) {
    int e = tid + l*256;
    int r = e >> 6, c = e & 63;
    Ks[r][c] = Kbase[(size_t)r*DM + c];
    Vs[r][c] = Vbase[(size_t)r*DM + c];
  }
  __syncthreads();
  int d = tid >> 2, m0 = (tid & 3) * 16;
  float acc[16] = {};
  for (int s = 0; s < CHUNK; ++s) {
    float kd = Ks[s][d];
#pragma unroll
    for (int j = 0; j < 16; ++j) acc[j] += kd * Vs[s][m0+j];
  }
  float* dst = kvst + (((size_t)(bh*NCH + ch)*64 + d)*64) + m0;
#pragma unroll
  for (int j = 0; j < 16; ++j) dst[j] = acc[j];
  if (tid < 64) {
    float s = 0;
    for (int r = 0; r < CHUNK; ++r) s += Ks[r][tid];
    ksum[(size_t)(bh*NCH + ch)*64 + tid] = s;
  }
}

// ---------------- attention pass B: per-chunk output, prefix summed on load ----------------
__global__ __launch_bounds__(256) void attn_chunk_out(
    const float* __restrict__ Qg, const float* __restrict__ Kg,
    const float* __restrict__ Vg, const float* __restrict__ kvst,
    const float* __restrict__ ksum, f16* __restrict__ O) {
  int ch = blockIdx.x, bh = blockIdx.y;
  int b = bh >> 3, h = bh & 7;
  __shared__ float Qs[CHUNK][64], Ks[CHUNK][64], Vs[CHUNK][64];
  __shared__ float kvp[64][64];
  __shared__ float Sl[CHUNK][CHUNK+1];
  __shared__ float ksp[64];
  __shared__ float den[CHUNK];
  int tid = threadIdx.x;
  const float* Qbase = Qg + ((size_t)(b*SEQ + ch*CHUNK))*DM + h*64;
  const float* Kbase = Kg + ((size_t)(b*SEQ + ch*CHUNK))*DM + h*64;
  const float* Vbase = Vg + ((size_t)(b*SEQ + ch*CHUNK))*DM + h*64;
#pragma unroll
  for (int ld = 0; ld < CHUNK*64/256; ++ld) {
    int e = tid + ld*256;
    int rr = e >> 6, cc = e & 63;
    Qs[rr][cc] = Qbase[(size_t)rr*DM + cc];
    Ks[rr][cc] = Kbase[(size_t)rr*DM + cc];
    Vs[rr][cc] = Vbase[(size_t)rr*DM + cc];
  }
  // kv prefix state = sum of previous chunks' sums (coalesced, L2/L3-resident)
  {
    const float* src = kvst + (size_t)bh*NCH*4096;
#pragma unroll
    for (int ld = 0; ld < 16; ++ld) {
      int e = tid + ld*256;
      float s = 0.0f;
      for (int cp = 0; cp < ch; ++cp) s += src[(size_t)cp*4096 + e];
      ((float*)kvp)[e] = s;
    }
  }
  if (tid < 64) {
    float s = 0.0f;
    const float* src = ksum + (size_t)bh*NCH*64;
    for (int cp = 0; cp < ch; ++cp) s += src[(size_t)cp*64 + tid];
    ksp[tid] = s;
  }
  __syncthreads();
#pragma unroll
  for (int ld = 0; ld < 4; ++ld) {
    int e = tid + ld*256;
    int i = e >> 5, j = e & 31;
    float s = 0;
    for (int d2 = 0; d2 < 64; ++d2) s += Qs[i][d2] * Ks[j][d2];
    Sl[i][j] = s;
  }
  __syncthreads();
  if (tid < CHUNK) {
    int i = tid;
    float dsum = 0;
    for (int d2 = 0; d2 < 64; ++d2) dsum += Qs[i][d2] * ksp[d2];
    for (int j = 0; j <= i; ++j) dsum += Sl[i][j];
    den[i] = 1.0f / (dsum + 1e-6f);
  }
  __syncthreads();
  int row = tid >> 3, m0 = (tid & 7) * 8;
  float acc[8] = {};
  for (int d2 = 0; d2 < 64; ++d2) {
    float qd = Qs[row][d2];
#pragma unroll
    for (int j = 0; j < 8; ++j) acc[j] += qd * kvp[d2][m0+j];
  }
  for (int j2 = 0; j2 <= row; ++j2) {
    float sv = Sl[row][j2];
#pragma unroll
    for (int j = 0; j < 8; ++j) acc[j] += sv * Vs[j2][m0+j];
  }
  float zi = den[row];
  f16* dst = O + ((size_t)(b*SEQ + ch*CHUNK + row))*DM + h*64 + m0;
#pragma unroll
  for (int j = 0; j < 8; ++j) dst[j] = (f16)(acc[j] * zi);
}

// ---------------- residual + layernorm (dual fp32 + f16 output) ----------------
__global__ __launch_bounds__(256) void resid_ln(
    const float* __restrict__ x, const float* __restrict__ r,
    const float* __restrict__ g, const float* __restrict__ bb,
    float* __restrict__ out, f16* __restrict__ out16) {
  int t = blockIdx.x;
  int tid = threadIdx.x;
  __shared__ float red[256];
  const float* xb = x + (size_t)t*DM;
  float v0 = xb[tid];
  float v1 = xb[tid+256];
  if (r) {
    const float* rb = r + (size_t)t*DM;
    v0 += rb[tid];
    v1 += rb[tid+256];
  }
  red[tid] = v0 + v1;
  __syncthreads();
  for (int o = 128; o > 0; o >>= 1) {
    if (tid < o) red[tid] += red[tid+o];
    __syncthreads();
  }
  float mean = red[0] * (1.0f/512.0f);
  __syncthreads();
  float d0 = v0 - mean, d1 = v1 - mean;
  red[tid] = d0*d0 + d1*d1;
  __syncthreads();
  for (int o = 128; o > 0; o >>= 1) {
    if (tid < o) red[tid] += red[tid+o];
    __syncthreads();
  }
  float rs = rsqrtf(red[0] * (1.0f/512.0f) + 1e-5f);
  float r0 = d0*rs*g[tid]     + bb[tid];
  float r1 = d1*rs*g[tid+256] + bb[tid+256];
  out[(size_t)t*DM + tid]     = r0;
  out[(size_t)t*DM + tid+256] = r1;
  if (out16) {
    out16[(size_t)t*DM + tid]     = (f16)r0;
    out16[(size_t)t*DM + tid+256] = (f16)r1;
  }
}

// ---------------- collapsed output heads (parallel) ----------------
struct HeadPtrs {
  const float* pw[6]; const float* pb[6];
  const float* vw[6]; const float* vb[6];
};

__global__ __launch_bounds__(64) void head_u_par(HeadPtrs hp, float* __restrict__ U,
                                                 float* __restrict__ Cc) {
  const int vsz[6] = {56, 135, 18, 87, 18, 25};
  const int off[6] = {0, 56, 191, 209, 296, 314};
  int d = blockIdx.x;          // 0..511 -> U[d]; 512 -> Cc
  int tid = threadIdx.x;
  float acc = 0.0f;
  for (int jj = tid; jj < 339; jj += 64) {
    int i;
    if (jj < 191) i = (jj < 56) ? 0 : 1;
    else if (jj < 296) i = (jj < 209) ? 2 : 3;
    else i = (jj < 314) ? 4 : 5;
    int j = jj - off[i];
    float wv = (d < 512) ? hp.pw[i][(size_t)d * vsz[i] + j] : hp.pb[i][j];
    acc += wv * hp.vw[i][j];
  }
#pragma unroll
  for (int s = 32; s > 0; s >>= 1) acc += __shfl_down(acc, s);
  if (tid == 0) {
    if (d < 512) U[d] = acc;
    else {
      for (int i = 0; i < 6; ++i) acc += hp.vb[i][0];
      Cc[0] = acc;
    }
  }
}

__global__ __launch_bounds__(512) void final_out(
    const float* __restrict__ hf, const float* __restrict__ U,
    const float* __restrict__ Cc, float* __restrict__ out) {
  int b = blockIdx.x;
  int d = threadIdx.x;
  __shared__ float red[512];
  float cs = 0;
  const float* hb = hf + (size_t)b*SEQ*DM + d;
  for (int s = 0; s < SEQ; ++s) cs += hb[(size_t)s*DM];
  red[d] = cs * U[d];
  __syncthreads();
  for (int o = 256; o > 0; o >>= 1) {
    if (d < o) red[d] += red[d+o];
    __syncthreads();
  }
  if (d == 0) out[b] = (red[0] * (1.0f/512.0f) + Cc[0]) * (1.0f/6.0f);
}

// ---------------- launch ----------------
extern "C" void kernel_launch(void* const* d_in, const int* in_sizes, int n_in,
                              void* d_out, int out_size, void* d_ws, size_t ws_size,
                              hipStream_t stream) {
  const int*   x    = (const int*)d_in[0];
  const float* T0   = (const float*)d_in[1];
  const float* T1   = (const float*)d_in[2];
  const float* T2   = (const float*)d_in[3];
  const float* T3   = (const float*)d_in[4];
  const float* T4   = (const float*)d_in[5];
  const float* T5   = (const float*)d_in[6];
  const float* in_w = (const float*)d_in[7];
  const float* in_b = (const float*)d_in[8];
  const float* Wq   = (const float*)d_in[9];
  const float* Wk   = (const float*)d_in[10];
  const float* Wv   = (const float*)d_in[11];
  const float* Wo   = (const float*)d_in[12];
  const float* W1   = (const float*)d_in[13];
  const float* W2   = (const float*)d_in[14];
  const float* bq   = (const float*)d_in[15];
  const float* bk   = (const float*)d_in[16];
  const float* bv   = (const float*)d_in[17];
  const float* bo   = (const float*)d_in[18];
  const float* bf1  = (const float*)d_in[19];
  const float* bf2  = (const float*)d_in[20];
  const float* b1n  = (const float*)d_in[21];
  const float* b2n  = (const float*)d_in[22];
  const float* g1   = (const float*)d_in[23];
  const float* g2   = (const float*)d_in[24];
  const float* gf   = (const float*)d_in[25];
  const float* bfn  = (const float*)d_in[26];
  HeadPtrs hp;
  for (int i = 0; i < 6; ++i) {
    hp.pw[i] = (const float*)d_in[27 + i*4];
    hp.pb[i] = (const float*)d_in[28 + i*4];
    hp.vw[i] = (const float*)d_in[29 + i*4];
    hp.vb[i] = (const float*)d_in[30 + i*4];
  }

  float* ws   = (float*)d_ws;
  float* h    = ws;                 // 1024*512 fp32
  float* q    = h    + 524288;
  float* k    = q    + 524288;
  float* v    = k    + 524288;
  float* a2   = v    + 524288;
  float* h2   = a2   + 524288;
  float* y    = h2   + 524288;
  float* kvst = y    + 524288;      // 16*16*64*64
  float* ksum = kvst + 1048576;     // 16*16*64
  float* U    = ksum + 16384;
  float* Cc   = U    + 512;
  f16* E16    = (f16*)(Cc + 16);    // 1024*1216
  f16* hf16   = E16   + 1245184;    // 1024*512
  f16* h2f16  = hf16  + 524288;
  f16* attn16 = h2f16 + 524288;
  f16* ff16   = attn16+ 524288;     // 1024*2048
  f16* in_wt  = ff16  + 2097152;    // 512*1216
  f16* qkvw   = in_wt + 623616;     // 12*1536*512
  f16* wot    = qkvw  + 9437184;    // 12*512*512
  f16* w1t    = wot   + 3145728;    // 12*2048*512
  f16* w2t    = w1t   + 12582912;   // 12*512*2048

  // weight conversion
  transp_convert<<<dim3(38,16,1),  256, 0, stream>>>(in_w, in_wt, 1216, 512, 0, 0);
  transp_convert_qkvo<<<dim3(16,16,48), 256, 0, stream>>>(Wq, Wk, Wv, Wo, qkvw, wot);
  transp_convert<<<dim3(16,64,12), 256, 0, stream>>>(W1, w1t,  512, 2048, 1048576, 1048576);
  transp_convert<<<dim3(64,16,12), 256, 0, stream>>>(W2, w2t, 2048,  512, 1048576, 1048576);

  embed_gather<<<TOK, 256, 0, stream>>>(x, T0, T1, T2, T3, T4, T5, E16);
  // input GEMM + bias + positional encoding, dual fp32/f16 out
  mfma_gemm<3><<<dim3(16,8), 256, 0, stream>>>(E16, in_wt, in_b, nullptr, nullptr,
                                               h, (float*)hf16, nullptr, TOK, 1216, 512);

  for (int l = 0; l < 12; ++l) {
    mfma_gemm<2><<<dim3(16,24), 256, 0, stream>>>(hf16, qkvw + (size_t)l*786432,
        bq + l*512, bk + l*512, bv + l*512, q, k, v, TOK, 512, 1536);
    attn_chunk_sums<<<dim3(NCH,16), 256, 0, stream>>>(k, v, kvst, ksum);
    attn_chunk_out<<<dim3(NCH,16), 256, 0, stream>>>(q, k, v, kvst, ksum, attn16);
    mfma_gemm<0><<<dim3(16,8), 256, 0, stream>>>(attn16, wot + (size_t)l*262144,
        bo + l*512, nullptr, nullptr, a2, nullptr, nullptr, TOK, 512, 512);
    resid_ln<<<TOK, 256, 0, stream>>>(h, a2, g1 + l*512, b1n + l*512, h2, h2f16);
    mfma_gemm<1><<<dim3(16,32), 256, 0, stream>>>(h2f16, w1t + (size_t)l*1048576,
        bf1 + l*2048, nullptr, nullptr, (float*)ff16, nullptr, nullptr, TOK, 512, 2048);
    mfma_gemm<0><<<dim3(16,8), 256, 0, stream>>>(ff16, w2t + (size_t)l*1048576,
        bf2 + l*512, nullptr, nullptr, y, nullptr, nullptr, TOK, 2048, 512);
    resid_ln<<<TOK, 256, 0, stream>>>(h2, y, g2 + l*512, b2n + l*512, h, hf16);
  }

  resid_ln<<<TOK, 256, 0, stream>>>(h, nullptr, gf, bfn, h2, nullptr);
  head_u_par<<<513, 64, 0, stream>>>(hp, U, Cc);
  final_out<<<NB, 512, 0, stream>>>(h2, U, Cc, (float*)d_out);
}

// Round 6
// 1523.579 us; speedup vs baseline: 2.4586x; 1.5284x over previous
//
#include <hip/hip_runtime.h>
#include <math.h>

typedef _Float16 f16;
typedef _Float16 f16x8 __attribute__((ext_vector_type(8)));
typedef float f32x4 __attribute__((ext_vector_type(4)));

#define TOK 1024   // B*S
#define DM  512
#define SEQ 512
#define NB  2
#define CHUNK 32
#define NCH (SEQ/CHUNK)   // 16

// ---------------- embedding gather (writes f16) ----------------
__global__ __launch_bounds__(256) void embed_gather(
    const int* __restrict__ x,
    const float* __restrict__ t0, const float* __restrict__ t1,
    const float* __restrict__ t2, const float* __restrict__ t3,
    const float* __restrict__ t4, const float* __restrict__ t5,
    f16* __restrict__ E) {
  int t = blockIdx.x;
  int tid = threadIdx.x;
  const int* xb = x + t * 6;
  for (int c = tid; c < 1216; c += 256) {
    float val;
    if (c < 128)       val = t0[xb[0]*128 + c]        * 11.313708498984761f;
    else if (c < 384)  val = t1[xb[1]*256 + (c-128)]  * 16.0f;
    else if (c < 448)  val = t2[xb[2]*64  + (c-384)]  * 8.0f;
    else if (c < 960)  val = t3[xb[3]*512 + (c-448)]  * 22.627416997969522f;
    else if (c < 1088) val = t4[xb[4]*128 + (c-960)]  * 11.313708498984761f;
    else               val = t5[xb[5]*128 + (c-1088)] * 11.313708498984761f;
    E[(size_t)t*1216 + c] = (f16)val;
  }
}

// ---------------- weight fp32 -> fp16 transpose-convert ----------------
__global__ __launch_bounds__(256) void transp_convert(
    const float* __restrict__ in, f16* __restrict__ out,
    int K, int N, size_t instride, size_t outstride) {
  int lz = blockIdx.z;
  const float* I = in + (size_t)lz * instride;
  f16* O = out + (size_t)lz * outstride;
  __shared__ float tile[32][33];
  int k0 = blockIdx.x * 32, n0 = blockIdx.y * 32;
  int tid = threadIdx.x;
  int cr = tid >> 5, cc = tid & 31;
#pragma unroll
  for (int p = 0; p < 4; ++p)
    tile[cr + p*8][cc] = I[(size_t)(k0 + cr + p*8) * N + n0 + cc];
  __syncthreads();
#pragma unroll
  for (int p = 0; p < 4; ++p)
    O[(size_t)(n0 + cr + p*8) * K + k0 + cc] = (f16)tile[cc][cr + p*8];
}

// combined Wq/Wk/Wv/Wo conversion: z = layer*4 + which
__global__ __launch_bounds__(256) void transp_convert_qkvo(
    const float* __restrict__ Wq, const float* __restrict__ Wk,
    const float* __restrict__ Wv, const float* __restrict__ Wo,
    f16* __restrict__ qkvw, f16* __restrict__ wot) {
  int z = blockIdx.z;
  int lz = z >> 2, m = z & 3;
  const float* I = ((m == 0) ? Wq : (m == 1) ? Wk : (m == 2) ? Wv : Wo)
                   + (size_t)lz * 262144;
  f16* O = (m < 3) ? qkvw + (size_t)lz * 786432 + (size_t)m * 262144
                   : wot + (size_t)lz * 262144;
  __shared__ float tile[32][33];
  int k0 = blockIdx.x * 32, n0 = blockIdx.y * 32;
  int tid = threadIdx.x;
  int cr = tid >> 5, cc = tid & 31;
#pragma unroll
  for (int p = 0; p < 4; ++p)
    tile[cr + p*8][cc] = I[(size_t)(k0 + cr + p*8) * 512 + n0 + cc];
  __syncthreads();
#pragma unroll
  for (int p = 0; p < 4; ++p)
    O[(size_t)(n0 + cr + p*8) * 512 + k0 + cc] = (f16)tile[cc][cr + p*8];
}

// ---------------- fp16 MFMA GEMM + fused epilogues ----------------
// E=0: bias -> fp32 o0
// E=1: bias + exact gelu -> f16 (o0 cast)
// E=2: QKV fused epilogue (elu+1 on q,k)
// E=3: bias + positional encoding -> fp32 o0 AND f16 o1
template<int E>
__global__ __launch_bounds__(256) void mfma_gemm(
    const f16* __restrict__ A, const f16* __restrict__ Bt,
    const float* __restrict__ b0, const float* __restrict__ b1,
    const float* __restrict__ b2,
    float* __restrict__ o0, float* __restrict__ o1, float* __restrict__ o2,
    int M, int K, int N) {
  __shared__ f16 As[64][72];
  __shared__ f16 Bs[64][72];
  const int tid = threadIdx.x;
  const int m0 = blockIdx.x * 64, n0 = blockIdx.y * 64;
  const int w = tid >> 6, l = tid & 63;
  const int wr = w >> 1, wc = w & 1;
  const int g = l >> 4, r = l & 15;
  const int lr = tid >> 2, lc = (tid & 3) * 8;
  f32x4 acc[2][2] = {};
  const f16* Ap = A + (size_t)(m0 + lr) * K + lc;
  const f16* Bp = Bt + (size_t)(n0 + lr) * K + lc;
  for (int k0 = 0; k0 < K; k0 += 64) {
    *(f16x8*)&As[lr][lc]      = *(const f16x8*)(Ap + k0);
    *(f16x8*)&As[lr][lc + 32] = *(const f16x8*)(Ap + k0 + 32);
    *(f16x8*)&Bs[lr][lc]      = *(const f16x8*)(Bp + k0);
    *(f16x8*)&Bs[lr][lc + 32] = *(const f16x8*)(Bp + k0 + 32);
    __syncthreads();
#pragma unroll
    for (int kk = 0; kk < 2; ++kk) {
      f16x8 a0  = *(const f16x8*)&As[wr*32 + r][kk*32 + g*8];
      f16x8 a1  = *(const f16x8*)&As[wr*32 + 16 + r][kk*32 + g*8];
      f16x8 bv0 = *(const f16x8*)&Bs[wc*32 + r][kk*32 + g*8];
      f16x8 bv1 = *(const f16x8*)&Bs[wc*32 + 16 + r][kk*32 + g*8];
      acc[0][0] = __builtin_amdgcn_mfma_f32_16x16x32_f16(a0, bv0, acc[0][0], 0, 0, 0);
      acc[0][1] = __builtin_amdgcn_mfma_f32_16x16x32_f16(a0, bv1, acc[0][1], 0, 0, 0);
      acc[1][0] = __builtin_amdgcn_mfma_f32_16x16x32_f16(a1, bv0, acc[1][0], 0, 0, 0);
      acc[1][1] = __builtin_amdgcn_mfma_f32_16x16x32_f16(a1, bv1, acc[1][1], 0, 0, 0);
    }
    __syncthreads();
  }
#pragma unroll
  for (int m = 0; m < 2; ++m) {
    int row = m0 + wr*32 + m*16 + g*4;
#pragma unroll
    for (int n = 0; n < 2; ++n) {
      int col = n0 + wc*32 + n*16 + r;
      float pediv = 0.0f;
      if (E == 3) pediv = __expf((float)(col >> 1) * (-0.035977892070386504f));
#pragma unroll
      for (int i = 0; i < 4; ++i) {
        float v = acc[m][n][i];
        if (E == 2) {
          int which = col >> 9;
          int lc2 = col & 511;
          const float* bb = (which == 0) ? b0 : (which == 1) ? b1 : b2;
          float* oo = (which == 0) ? o0 : (which == 1) ? o1 : o2;
          v += bb[lc2];
          if (which < 2) v = (v > 0.0f) ? v + 1.0f : __expf(v);
          oo[(size_t)(row + i) * 512 + lc2] = v;
        } else if (E == 1) {
          v += b0[col];
          v = 0.5f * v * (1.0f + erff(v * 0.70710678118654752f));
          ((f16*)o0)[(size_t)(row + i) * N + col] = (f16)v;
        } else if (E == 3) {
          v += b0[col];
          float ang = (float)((row + i) & (SEQ-1)) * pediv;
          v += (col & 1) ? cosf(ang) : sinf(ang);
          o0[(size_t)(row + i) * N + col] = v;
          ((f16*)o1)[(size_t)(row + i) * N + col] = (f16)v;
        } else {
          v += b0[col];
          o0[(size_t)(row + i) * N + col] = v;
        }
      }
    }
  }
}

// ---------------- attention pass A: per-chunk KV / K sums (parallel) ----------------
__global__ __launch_bounds__(256) void attn_chunk_sums(
    const float* __restrict__ Kg, const float* __restrict__ Vg,
    float* __restrict__ kvst, float* __restrict__ ksum) {
  int ch = blockIdx.x, bh = blockIdx.y;
  int b = bh >> 3, h = bh & 7;
  __shared__ float Ks[CHUNK][65], Vs[CHUNK][65];
  int tid = threadIdx.x;
  const float* Kbase = Kg + ((size_t)(b*SEQ + ch*CHUNK))*DM + h*64;
  const float* Vbase = Vg + ((size_t)(b*SEQ + ch*CHUNK))*DM + h*64;
#pragma unroll
  for (int l = 0; l < CHUNK*64/256; ++l) {
    int e = tid + l*256;
    int r = e >> 6, c = e & 63;
    Ks[r][c] = Kbase[(size_t)r*DM + c];
    Vs[r][c] = Vbase[(size_t)r*DM + c];
  }
  __syncthreads();
  int d = tid >> 2, m0 = (tid & 3) * 16;
  float acc[16] = {};
  for (int s = 0; s < CHUNK; ++s) {
    float kd = Ks[s][d];
#pragma unroll
    for (int j = 0; j < 16; ++j) acc[j] += kd * Vs[s][m0+j];
  }
  float* dst = kvst + (((size_t)(bh*NCH + ch)*64 + d)*64) + m0;
#pragma unroll
  for (int j4 = 0; j4 < 4; ++j4)
    *(float4*)(dst + j4*4) = make_float4(acc[j4*4], acc[j4*4+1], acc[j4*4+2], acc[j4*4+3]);
  if (tid < 64) {
    float s = 0;
    for (int r = 0; r < CHUNK; ++r) s += Ks[r][tid];
    ksum[(size_t)(bh*NCH + ch)*64 + tid] = s;
  }
}

// ---------------- attention pass B: parallel exclusive prefix scan ----------------
// grid (17, 16): slices 0-15 scan kvst (256 elems each), slice 16 scans ksum
__global__ __launch_bounds__(256) void attn_scan_par(
    float* __restrict__ kvst, float* __restrict__ ksum) {
  int slice = blockIdx.x;
  int bh = blockIdx.y;
  int tid = threadIdx.x;
  if (slice < 16) {
    size_t base = (size_t)bh*NCH*4096 + slice*256 + tid;
    float run = 0.0f;
    for (int ch = 0; ch < NCH; ++ch) {
      size_t idx = base + (size_t)ch*4096;
      float t = kvst[idx];
      kvst[idx] = run;
      run += t;
    }
  } else if (tid < 64) {
    size_t base = (size_t)bh*NCH*64 + tid;
    float run = 0.0f;
    for (int ch = 0; ch < NCH; ++ch) {
      size_t idx = base + (size_t)ch*64;
      float t = ksum[idx];
      ksum[idx] = run;
      run += t;
    }
  }
}

// ---------------- attention pass C: per-chunk output (bank-conflict-free) ----------------
__global__ __launch_bounds__(256) void attn_chunk_out(
    const float* __restrict__ Qg, const float* __restrict__ Kg,
    const float* __restrict__ Vg, const float* __restrict__ kvst,
    const float* __restrict__ ksum, f16* __restrict__ O) {
  int ch = blockIdx.x, bh = blockIdx.y;
  int b = bh >> 3, h = bh & 7;
  __shared__ float Qs[CHUNK][65], Ks[CHUNK][65], Vs[CHUNK][65];
  __shared__ float kvp[64][65];
  __shared__ float Sl[CHUNK][CHUNK+1];
  __shared__ float ksp[64];
  __shared__ float den[CHUNK];
  int tid = threadIdx.x;
  const float* Qbase = Qg + ((size_t)(b*SEQ + ch*CHUNK))*DM + h*64;
  const float* Kbase = Kg + ((size_t)(b*SEQ + ch*CHUNK))*DM + h*64;
  const float* Vbase = Vg + ((size_t)(b*SEQ + ch*CHUNK))*DM + h*64;
#pragma unroll
  for (int ld = 0; ld < CHUNK*64/256; ++ld) {
    int e = tid + ld*256;
    int rr = e >> 6, cc = e & 63;
    Qs[rr][cc] = Qbase[(size_t)rr*DM + cc];
    Ks[rr][cc] = Kbase[(size_t)rr*DM + cc];
    Vs[rr][cc] = Vbase[(size_t)rr*DM + cc];
  }
  {
    const float* src = kvst + (size_t)(bh*NCH + ch)*4096;
#pragma unroll
    for (int ld = 0; ld < 16; ++ld) {
      int e = tid + ld*256;
      kvp[e >> 6][e & 63] = src[e];
    }
  }
  if (tid < 64) ksp[tid] = ksum[(size_t)(bh*NCH + ch)*64 + tid];
  __syncthreads();
  // S = Q K^T within chunk
#pragma unroll
  for (int ld = 0; ld < 4; ++ld) {
    int e = tid + ld*256;
    int i = e >> 5, j = e & 31;
    float s = 0;
    for (int d2 = 0; d2 < 64; ++d2) s += Qs[i][d2] * Ks[j][d2];
    Sl[i][j] = s;
  }
  __syncthreads();
  if (tid < CHUNK) {
    int i = tid;
    float dsum = 0;
    for (int d2 = 0; d2 < 64; ++d2) dsum += Qs[i][d2] * ksp[d2];
    for (int j = 0; j <= i; ++j) dsum += Sl[i][j];
    den[i] = 1.0f / (dsum + 1e-6f);
  }
  __syncthreads();
  int row = tid >> 3, m0 = (tid & 7) * 8;
  float acc[8] = {};
  for (int d2 = 0; d2 < 64; ++d2) {
    float qd = Qs[row][d2];
#pragma unroll
    for (int j = 0; j < 8; ++j) acc[j] += qd * kvp[d2][m0+j];
  }
  for (int j2 = 0; j2 <= row; ++j2) {
    float sv = Sl[row][j2];
#pragma unroll
    for (int j = 0; j < 8; ++j) acc[j] += sv * Vs[j2][m0+j];
  }
  float zi = den[row];
  f16* dst = O + ((size_t)(b*SEQ + ch*CHUNK + row))*DM + h*64 + m0;
#pragma unroll
  for (int j = 0; j < 8; ++j) dst[j] = (f16)(acc[j] * zi);
}

// ---------------- residual + layernorm (dual fp32 + f16 output) ----------------
__global__ __launch_bounds__(256) void resid_ln(
    const float* __restrict__ x, const float* __restrict__ r,
    const float* __restrict__ g, const float* __restrict__ bb,
    float* __restrict__ out, f16* __restrict__ out16) {
  int t = blockIdx.x;
  int tid = threadIdx.x;
  __shared__ float red[256];
  const float* xb = x + (size_t)t*DM;
  float v0 = xb[tid];
  float v1 = xb[tid+256];
  if (r) {
    const float* rb = r + (size_t)t*DM;
    v0 += rb[tid];
    v1 += rb[tid+256];
  }
  red[tid] = v0 + v1;
  __syncthreads();
  for (int o = 128; o > 0; o >>= 1) {
    if (tid < o) red[tid] += red[tid+o];
    __syncthreads();
  }
  float mean = red[0] * (1.0f/512.0f);
  __syncthreads();
  float d0 = v0 - mean, d1 = v1 - mean;
  red[tid] = d0*d0 + d1*d1;
  __syncthreads();
  for (int o = 128; o > 0; o >>= 1) {
    if (tid < o) red[tid] += red[tid+o];
    __syncthreads();
  }
  float rs = rsqrtf(red[0] * (1.0f/512.0f) + 1e-5f);
  float r0 = d0*rs*g[tid]     + bb[tid];
  float r1 = d1*rs*g[tid+256] + bb[tid+256];
  out[(size_t)t*DM + tid]     = r0;
  out[(size_t)t*DM + tid+256] = r1;
  if (out16) {
    out16[(size_t)t*DM + tid]     = (f16)r0;
    out16[(size_t)t*DM + tid+256] = (f16)r1;
  }
}

// ---------------- collapsed output heads (parallel) ----------------
struct HeadPtrs {
  const float* pw[6]; const float* pb[6];
  const float* vw[6]; const float* vb[6];
};

__global__ __launch_bounds__(64) void head_u_par(HeadPtrs hp, float* __restrict__ U,
                                                 float* __restrict__ Cc) {
  const int vsz[6] = {56, 135, 18, 87, 18, 25};
  const int off[6] = {0, 56, 191, 209, 296, 314};
  int d = blockIdx.x;          // 0..511 -> U[d]; 512 -> Cc
  int tid = threadIdx.x;
  float acc = 0.0f;
  for (int jj = tid; jj < 339; jj += 64) {
    int i;
    if (jj < 191) i = (jj < 56) ? 0 : 1;
    else if (jj < 296) i = (jj < 209) ? 2 : 3;
    else i = (jj < 314) ? 4 : 5;
    int j = jj - off[i];
    float wv = (d < 512) ? hp.pw[i][(size_t)d * vsz[i] + j] : hp.pb[i][j];
    acc += wv * hp.vw[i][j];
  }
#pragma unroll
  for (int s = 32; s > 0; s >>= 1) acc += __shfl_down(acc, s);
  if (tid == 0) {
    if (d < 512) U[d] = acc;
    else {
      for (int i = 0; i < 6; ++i) acc += hp.vb[i][0];
      Cc[0] = acc;
    }
  }
}

__global__ __launch_bounds__(512) void final_out(
    const float* __restrict__ hf, const float* __restrict__ U,
    const float* __restrict__ Cc, float* __restrict__ out) {
  int b = blockIdx.x;
  int d = threadIdx.x;
  __shared__ float red[512];
  float cs = 0;
  const float* hb = hf + (size_t)b*SEQ*DM + d;
  for (int s = 0; s < SEQ; ++s) cs += hb[(size_t)s*DM];
  red[d] = cs * U[d];
  __syncthreads();
  for (int o = 256; o > 0; o >>= 1) {
    if (d < o) red[d] += red[d+o];
    __syncthreads();
  }
  if (d == 0) out[b] = (red[0] * (1.0f/512.0f) + Cc[0]) * (1.0f/6.0f);
}

// ---------------- launch ----------------
extern "C" void kernel_launch(void* const* d_in, const int* in_sizes, int n_in,
                              void* d_out, int out_size, void* d_ws, size_t ws_size,
                              hipStream_t stream) {
  const int*   x    = (const int*)d_in[0];
  const float* T0   = (const float*)d_in[1];
  const float* T1   = (const float*)d_in[2];
  const float* T2   = (const float*)d_in[3];
  const float* T3   = (const float*)d_in[4];
  const float* T4   = (const float*)d_in[5];
  const float* T5   = (const float*)d_in[6];
  const float* in_w = (const float*)d_in[7];
  const float* in_b = (const float*)d_in[8];
  const float* Wq   = (const float*)d_in[9];
  const float* Wk   = (const float*)d_in[10];
  const float* Wv   = (const float*)d_in[11];
  const float* Wo   = (const float*)d_in[12];
  const float* W1   = (const float*)d_in[13];
  const float* W2   = (const float*)d_in[14];
  const float* bq   = (const float*)d_in[15];
  const float* bk   = (const float*)d_in[16];
  const float* bv   = (const float*)d_in[17];
  const float* bo   = (const float*)d_in[18];
  const float* bf1  = (const float*)d_in[19];
  const float* bf2  = (const float*)d_in[20];
  const float* b1n  = (const float*)d_in[21];
  const float* b2n  = (const float*)d_in[22];
  const float* g1   = (const float*)d_in[23];
  const float* g2   = (const float*)d_in[24];
  const float* gf   = (const float*)d_in[25];
  const float* bfn  = (const float*)d_in[26];
  HeadPtrs hp;
  for (int i = 0; i < 6; ++i) {
    hp.pw[i] = (const float*)d_in[27 + i*4];
    hp.pb[i] = (const float*)d_in[28 + i*4];
    hp.vw[i] = (const float*)d_in[29 + i*4];
    hp.vb[i] = (const float*)d_in[30 + i*4];
  }

  float* ws   = (float*)d_ws;
  float* h    = ws;                 // 1024*512 fp32
  float* q    = h    + 524288;
  float* k    = q    + 524288;
  float* v    = k    + 524288;
  float* a2   = v    + 524288;
  float* h2   = a2   + 524288;
  float* y    = h2   + 524288;
  float* kvst = y    + 524288;      // 16*16*64*64
  float* ksum = kvst + 1048576;     // 16*16*64
  float* U    = ksum + 16384;
  float* Cc   = U    + 512;
  f16* E16    = (f16*)(Cc + 16);    // 1024*1216
  f16* hf16   = E16   + 1245184;    // 1024*512
  f16* h2f16  = hf16  + 524288;
  f16* attn16 = h2f16 + 524288;
  f16* ff16   = attn16+ 524288;     // 1024*2048
  f16* in_wt  = ff16  + 2097152;    // 512*1216
  f16* qkvw   = in_wt + 623616;     // 12*1536*512
  f16* wot    = qkvw  + 9437184;    // 12*512*512
  f16* w1t    = wot   + 3145728;    // 12*2048*512
  f16* w2t    = w1t   + 12582912;   // 12*512*2048

  // weight conversion
  transp_convert<<<dim3(38,16,1),  256, 0, stream>>>(in_w, in_wt, 1216, 512, 0, 0);
  transp_convert_qkvo<<<dim3(16,16,48), 256, 0, stream>>>(Wq, Wk, Wv, Wo, qkvw, wot);
  transp_convert<<<dim3(16,64,12), 256, 0, stream>>>(W1, w1t,  512, 2048, 1048576, 1048576);
  transp_convert<<<dim3(64,16,12), 256, 0, stream>>>(W2, w2t, 2048,  512, 1048576, 1048576);

  embed_gather<<<TOK, 256, 0, stream>>>(x, T0, T1, T2, T3, T4, T5, E16);
  // input GEMM + bias + positional encoding, dual fp32/f16 out
  mfma_gemm<3><<<dim3(16,8), 256, 0, stream>>>(E16, in_wt, in_b, nullptr, nullptr,
                                               h, (float*)hf16, nullptr, TOK, 1216, 512);

  for (int l = 0; l < 12; ++l) {
    mfma_gemm<2><<<dim3(16,24), 256, 0, stream>>>(hf16, qkvw + (size_t)l*786432,
        bq + l*512, bk + l*512, bv + l*512, q, k, v, TOK, 512, 1536);
    attn_chunk_sums<<<dim3(NCH,16), 256, 0, stream>>>(k, v, kvst, ksum);
    attn_scan_par<<<dim3(17,16), 256, 0, stream>>>(kvst, ksum);
    attn_chunk_out<<<dim3(NCH,16), 256, 0, stream>>>(q, k, v, kvst, ksum, attn16);
    mfma_gemm<0><<<dim3(16,8), 256, 0, stream>>>(attn16, wot + (size_t)l*262144,
        bo + l*512, nullptr, nullptr, a2, nullptr, nullptr, TOK, 512, 512);
    resid_ln<<<TOK, 256, 0, stream>>>(h, a2, g1 + l*512, b1n + l*512, h2, h2f16);
    mfma_gemm<1><<<dim3(16,32), 256, 0, stream>>>(h2f16, w1t + (size_t)l*1048576,
        bf1 + l*2048, nullptr, nullptr, (float*)ff16, nullptr, nullptr, TOK, 512, 2048);
    mfma_gemm<0><<<dim3(16,8), 256, 0, stream>>>(ff16, w2t + (size_t)l*1048576,
        bf2 + l*512, nullptr, nullptr, y, nullptr, nullptr, TOK, 2048, 512);
    resid_ln<<<TOK, 256, 0, stream>>>(h2, y, g2 + l*512, b2n + l*512, h, hf16);
  }

  resid_ln<<<TOK, 256, 0, stream>>>(h, nullptr, gf, bfn, h2, nullptr);
  head_u_par<<<513, 64, 0, stream>>>(hp, U, Cc);
  final_out<<<NB, 512, 0, stream>>>(h2, U, Cc, (float*)d_out);
}

// Round 7
// 1245.896 us; speedup vs baseline: 3.0066x; 1.2229x over previous
//
#include <hip/hip_runtime.h>
#include <math.h>

typedef _Float16 f16;
typedef _Float16 f16x8 __attribute__((ext_vector_type(8)));
typedef float f32x4 __attribute__((ext_vector_type(4)));

#define TOK 1024   // B*S
#define DM  512
#define SEQ 512
#define NB  2
#define CHUNK 32
#define NCH (SEQ/CHUNK)   // 16

// ---------------- embedding gather (writes f16) ----------------
__global__ __launch_bounds__(256) void embed_gather(
    const int* __restrict__ x,
    const float* __restrict__ t0, const float* __restrict__ t1,
    const float* __restrict__ t2, const float* __restrict__ t3,
    const float* __restrict__ t4, const float* __restrict__ t5,
    f16* __restrict__ E) {
  int t = blockIdx.x;
  int tid = threadIdx.x;
  const int* xb = x + t * 6;
  for (int c = tid; c < 1216; c += 256) {
    float val;
    if (c < 128)       val = t0[xb[0]*128 + c]        * 11.313708498984761f;
    else if (c < 384)  val = t1[xb[1]*256 + (c-128)]  * 16.0f;
    else if (c < 448)  val = t2[xb[2]*64  + (c-384)]  * 8.0f;
    else if (c < 960)  val = t3[xb[3]*512 + (c-448)]  * 22.627416997969522f;
    else if (c < 1088) val = t4[xb[4]*128 + (c-960)]  * 11.313708498984761f;
    else               val = t5[xb[5]*128 + (c-1088)] * 11.313708498984761f;
    E[(size_t)t*1216 + c] = (f16)val;
  }
}

// ---------------- weight fp32 -> fp16 transpose-convert ----------------
__global__ __launch_bounds__(256) void transp_convert(
    const float* __restrict__ in, f16* __restrict__ out,
    int K, int N, size_t instride, size_t outstride) {
  int lz = blockIdx.z;
  const float* I = in + (size_t)lz * instride;
  f16* O = out + (size_t)lz * outstride;
  __shared__ float tile[32][33];
  int k0 = blockIdx.x * 32, n0 = blockIdx.y * 32;
  int tid = threadIdx.x;
  int cr = tid >> 5, cc = tid & 31;
#pragma unroll
  for (int p = 0; p < 4; ++p)
    tile[cr + p*8][cc] = I[(size_t)(k0 + cr + p*8) * N + n0 + cc];
  __syncthreads();
#pragma unroll
  for (int p = 0; p < 4; ++p)
    O[(size_t)(n0 + cr + p*8) * K + k0 + cc] = (f16)tile[cc][cr + p*8];
}

// combined Wq/Wk/Wv/Wo conversion: z = layer*4 + which
__global__ __launch_bounds__(256) void transp_convert_qkvo(
    const float* __restrict__ Wq, const float* __restrict__ Wk,
    const float* __restrict__ Wv, const float* __restrict__ Wo,
    f16* __restrict__ qkvw, f16* __restrict__ wot) {
  int z = blockIdx.z;
  int lz = z >> 2, m = z & 3;
  const float* I = ((m == 0) ? Wq : (m == 1) ? Wk : (m == 2) ? Wv : Wo)
                   + (size_t)lz * 262144;
  f16* O = (m < 3) ? qkvw + (size_t)lz * 786432 + (size_t)m * 262144
                   : wot + (size_t)lz * 262144;
  __shared__ float tile[32][33];
  int k0 = blockIdx.x * 32, n0 = blockIdx.y * 32;
  int tid = threadIdx.x;
  int cr = tid >> 5, cc = tid & 31;
#pragma unroll
  for (int p = 0; p < 4; ++p)
    tile[cr + p*8][cc] = I[(size_t)(k0 + cr + p*8) * 512 + n0 + cc];
  __syncthreads();
#pragma unroll
  for (int p = 0; p < 4; ++p)
    O[(size_t)(n0 + cr + p*8) * 512 + k0 + cc] = (f16)tile[cc][cr + p*8];
}

// ---------------- fp16 MFMA GEMM + fused epilogues ----------------
// E=1: bias + exact gelu -> f16 (o0 cast)
// E=2: QKV fused epilogue (elu+1 on q,k)
// E=3: bias + positional encoding -> fp32 o0 AND f16 o1
template<int E>
__global__ __launch_bounds__(256) void mfma_gemm(
    const f16* __restrict__ A, const f16* __restrict__ Bt,
    const float* __restrict__ b0, const float* __restrict__ b1,
    const float* __restrict__ b2,
    float* __restrict__ o0, float* __restrict__ o1, float* __restrict__ o2,
    int M, int K, int N) {
  __shared__ f16 As[64][72];
  __shared__ f16 Bs[64][72];
  const int tid = threadIdx.x;
  const int m0 = blockIdx.x * 64, n0 = blockIdx.y * 64;
  const int w = tid >> 6, l = tid & 63;
  const int wr = w >> 1, wc = w & 1;
  const int g = l >> 4, r = l & 15;
  const int lr = tid >> 2, lc = (tid & 3) * 8;
  f32x4 acc[2][2] = {};
  const f16* Ap = A + (size_t)(m0 + lr) * K + lc;
  const f16* Bp = Bt + (size_t)(n0 + lr) * K + lc;
  for (int k0 = 0; k0 < K; k0 += 64) {
    *(f16x8*)&As[lr][lc]      = *(const f16x8*)(Ap + k0);
    *(f16x8*)&As[lr][lc + 32] = *(const f16x8*)(Ap + k0 + 32);
    *(f16x8*)&Bs[lr][lc]      = *(const f16x8*)(Bp + k0);
    *(f16x8*)&Bs[lr][lc + 32] = *(const f16x8*)(Bp + k0 + 32);
    __syncthreads();
#pragma unroll
    for (int kk = 0; kk < 2; ++kk) {
      f16x8 a0  = *(const f16x8*)&As[wr*32 + r][kk*32 + g*8];
      f16x8 a1  = *(const f16x8*)&As[wr*32 + 16 + r][kk*32 + g*8];
      f16x8 bv0 = *(const f16x8*)&Bs[wc*32 + r][kk*32 + g*8];
      f16x8 bv1 = *(const f16x8*)&Bs[wc*32 + 16 + r][kk*32 + g*8];
      acc[0][0] = __builtin_amdgcn_mfma_f32_16x16x32_f16(a0, bv0, acc[0][0], 0, 0, 0);
      acc[0][1] = __builtin_amdgcn_mfma_f32_16x16x32_f16(a0, bv1, acc[0][1], 0, 0, 0);
      acc[1][0] = __builtin_amdgcn_mfma_f32_16x16x32_f16(a1, bv0, acc[1][0], 0, 0, 0);
      acc[1][1] = __builtin_amdgcn_mfma_f32_16x16x32_f16(a1, bv1, acc[1][1], 0, 0, 0);
    }
    __syncthreads();
  }
#pragma unroll
  for (int m = 0; m < 2; ++m) {
    int row = m0 + wr*32 + m*16 + g*4;
#pragma unroll
    for (int n = 0; n < 2; ++n) {
      int col = n0 + wc*32 + n*16 + r;
      float pediv = 0.0f;
      if (E == 3) pediv = __expf((float)(col >> 1) * (-0.035977892070386504f));
#pragma unroll
      for (int i = 0; i < 4; ++i) {
        float v = acc[m][n][i];
        if (E == 2) {
          int which = col >> 9;
          int lc2 = col & 511;
          const float* bb = (which == 0) ? b0 : (which == 1) ? b1 : b2;
          float* oo = (which == 0) ? o0 : (which == 1) ? o1 : o2;
          v += bb[lc2];
          if (which < 2) v = (v > 0.0f) ? v + 1.0f : __expf(v);
          oo[(size_t)(row + i) * 512 + lc2] = v;
        } else if (E == 1) {
          v += b0[col];
          v = 0.5f * v * (1.0f + erff(v * 0.70710678118654752f));
          ((f16*)o0)[(size_t)(row + i) * N + col] = (f16)v;
        } else if (E == 3) {
          v += b0[col];
          float ang = (float)((row + i) & (SEQ-1)) * pediv;
          v += (col & 1) ? cosf(ang) : sinf(ang);
          o0[(size_t)(row + i) * N + col] = v;
          ((f16*)o1)[(size_t)(row + i) * N + col] = (f16)v;
        }
      }
    }
  }
}

// ---------------- split-K MFMA GEMM: partials, no bias ----------------
// P[z][M][N] += A[M][zKS:(z+1)KS] * Bt[N][zKS:(z+1)KS]^T
__global__ __launch_bounds__(256) void mfma_gemm_sk(
    const f16* __restrict__ A, const f16* __restrict__ Bt,
    float* __restrict__ P, int M, int K, int N, int KS) {
  __shared__ f16 As[64][72];
  __shared__ f16 Bs[64][72];
  const int tid = threadIdx.x;
  const int m0 = blockIdx.x * 64, n0 = blockIdx.y * 64;
  const int z = blockIdx.z;
  const int w = tid >> 6, l = tid & 63;
  const int wr = w >> 1, wc = w & 1;
  const int g = l >> 4, r = l & 15;
  const int lr = tid >> 2, lc = (tid & 3) * 8;
  f32x4 acc[2][2] = {};
  const f16* Ap = A + (size_t)(m0 + lr) * K + z*KS + lc;
  const f16* Bp = Bt + (size_t)(n0 + lr) * K + z*KS + lc;
  for (int k0 = 0; k0 < KS; k0 += 64) {
    *(f16x8*)&As[lr][lc]      = *(const f16x8*)(Ap + k0);
    *(f16x8*)&As[lr][lc + 32] = *(const f16x8*)(Ap + k0 + 32);
    *(f16x8*)&Bs[lr][lc]      = *(const f16x8*)(Bp + k0);
    *(f16x8*)&Bs[lr][lc + 32] = *(const f16x8*)(Bp + k0 + 32);
    __syncthreads();
#pragma unroll
    for (int kk = 0; kk < 2; ++kk) {
      f16x8 a0  = *(const f16x8*)&As[wr*32 + r][kk*32 + g*8];
      f16x8 a1  = *(const f16x8*)&As[wr*32 + 16 + r][kk*32 + g*8];
      f16x8 bv0 = *(const f16x8*)&Bs[wc*32 + r][kk*32 + g*8];
      f16x8 bv1 = *(const f16x8*)&Bs[wc*32 + 16 + r][kk*32 + g*8];
      acc[0][0] = __builtin_amdgcn_mfma_f32_16x16x32_f16(a0, bv0, acc[0][0], 0, 0, 0);
      acc[0][1] = __builtin_amdgcn_mfma_f32_16x16x32_f16(a0, bv1, acc[0][1], 0, 0, 0);
      acc[1][0] = __builtin_amdgcn_mfma_f32_16x16x32_f16(a1, bv0, acc[1][0], 0, 0, 0);
      acc[1][1] = __builtin_amdgcn_mfma_f32_16x16x32_f16(a1, bv1, acc[1][1], 0, 0, 0);
    }
    __syncthreads();
  }
  float* Pz = P + (size_t)z * M * N;
#pragma unroll
  for (int m = 0; m < 2; ++m) {
    int row = m0 + wr*32 + m*16 + g*4;
#pragma unroll
    for (int n = 0; n < 2; ++n) {
      int col = n0 + wc*32 + n*16 + r;
#pragma unroll
      for (int i = 0; i < 4; ++i)
        Pz[(size_t)(row + i) * N + col] = acc[m][n][i];
    }
  }
}

// ---------------- attention pass A: per-chunk KV / K sums (parallel) ----------------
__global__ __launch_bounds__(256) void attn_chunk_sums(
    const float* __restrict__ Kg, const float* __restrict__ Vg,
    float* __restrict__ kvst, float* __restrict__ ksum) {
  int ch = blockIdx.x, bh = blockIdx.y;
  int b = bh >> 3, h = bh & 7;
  __shared__ float Ks[CHUNK][65], Vs[CHUNK][65];
  int tid = threadIdx.x;
  const float* Kbase = Kg + ((size_t)(b*SEQ + ch*CHUNK))*DM + h*64;
  const float* Vbase = Vg + ((size_t)(b*SEQ + ch*CHUNK))*DM + h*64;
#pragma unroll
  for (int l = 0; l < CHUNK*64/256; ++l) {
    int e = tid + l*256;
    int r = e >> 6, c = e & 63;
    Ks[r][c] = Kbase[(size_t)r*DM + c];
    Vs[r][c] = Vbase[(size_t)r*DM + c];
  }
  __syncthreads();
  int d = tid >> 2, m0 = (tid & 3) * 16;
  float acc[16] = {};
  for (int s = 0; s < CHUNK; ++s) {
    float kd = Ks[s][d];
#pragma unroll
    for (int j = 0; j < 16; ++j) acc[j] += kd * Vs[s][m0+j];
  }
  float* dst = kvst + (((size_t)(bh*NCH + ch)*64 + d)*64) + m0;
#pragma unroll
  for (int j4 = 0; j4 < 4; ++j4)
    *(float4*)(dst + j4*4) = make_float4(acc[j4*4], acc[j4*4+1], acc[j4*4+2], acc[j4*4+3]);
  if (tid < 64) {
    float s = 0;
    for (int r = 0; r < CHUNK; ++r) s += Ks[r][tid];
    ksum[(size_t)(bh*NCH + ch)*64 + tid] = s;
  }
}

// ---------------- attention pass B: parallel exclusive prefix scan ----------------
__global__ __launch_bounds__(256) void attn_scan_par(
    float* __restrict__ kvst, float* __restrict__ ksum) {
  int slice = blockIdx.x;
  int bh = blockIdx.y;
  int tid = threadIdx.x;
  if (slice < 16) {
    size_t base = (size_t)bh*NCH*4096 + slice*256 + tid;
    float run = 0.0f;
    for (int ch = 0; ch < NCH; ++ch) {
      size_t idx = base + (size_t)ch*4096;
      float t = kvst[idx];
      kvst[idx] = run;
      run += t;
    }
  } else if (tid < 64) {
    size_t base = (size_t)bh*NCH*64 + tid;
    float run = 0.0f;
    for (int ch = 0; ch < NCH; ++ch) {
      size_t idx = base + (size_t)ch*64;
      float t = ksum[idx];
      ksum[idx] = run;
      run += t;
    }
  }
}

// ---------------- attention pass C: per-chunk output ----------------
__global__ __launch_bounds__(256) void attn_chunk_out(
    const float* __restrict__ Qg, const float* __restrict__ Kg,
    const float* __restrict__ Vg, const float* __restrict__ kvst,
    const float* __restrict__ ksum, f16* __restrict__ O) {
  int ch = blockIdx.x, bh = blockIdx.y;
  int b = bh >> 3, h = bh & 7;
  __shared__ float Qs[CHUNK][65], Ks[CHUNK][65], Vs[CHUNK][65];
  __shared__ float kvp[64][65];
  __shared__ float Sl[CHUNK][CHUNK+1];
  __shared__ float ksp[64];
  __shared__ float den[CHUNK];
  int tid = threadIdx.x;
  const float* Qbase = Qg + ((size_t)(b*SEQ + ch*CHUNK))*DM + h*64;
  const float* Kbase = Kg + ((size_t)(b*SEQ + ch*CHUNK))*DM + h*64;
  const float* Vbase = Vg + ((size_t)(b*SEQ + ch*CHUNK))*DM + h*64;
#pragma unroll
  for (int ld = 0; ld < CHUNK*64/256; ++ld) {
    int e = tid + ld*256;
    int rr = e >> 6, cc = e & 63;
    Qs[rr][cc] = Qbase[(size_t)rr*DM + cc];
    Ks[rr][cc] = Kbase[(size_t)rr*DM + cc];
    Vs[rr][cc] = Vbase[(size_t)rr*DM + cc];
  }
  {
    const float* src = kvst + (size_t)(bh*NCH + ch)*4096;
#pragma unroll
    for (int ld = 0; ld < 16; ++ld) {
      int e = tid + ld*256;
      kvp[e >> 6][e & 63] = src[e];
    }
  }
  if (tid < 64) ksp[tid] = ksum[(size_t)(bh*NCH + ch)*64 + tid];
  __syncthreads();
#pragma unroll
  for (int ld = 0; ld < 4; ++ld) {
    int e = tid + ld*256;
    int i = e >> 5, j = e & 31;
    float s = 0;
    for (int d2 = 0; d2 < 64; ++d2) s += Qs[i][d2] * Ks[j][d2];
    Sl[i][j] = s;
  }
  __syncthreads();
  if (tid < CHUNK) {
    int i = tid;
    float dsum = 0;
    for (int d2 = 0; d2 < 64; ++d2) dsum += Qs[i][d2] * ksp[d2];
    for (int j = 0; j <= i; ++j) dsum += Sl[i][j];
    den[i] = 1.0f / (dsum + 1e-6f);
  }
  __syncthreads();
  int row = tid >> 3, m0 = (tid & 7) * 8;
  float acc[8] = {};
  for (int d2 = 0; d2 < 64; ++d2) {
    float qd = Qs[row][d2];
#pragma unroll
    for (int j = 0; j < 8; ++j) acc[j] += qd * kvp[d2][m0+j];
  }
  for (int j2 = 0; j2 <= row; ++j2) {
    float sv = Sl[row][j2];
#pragma unroll
    for (int j = 0; j < 8; ++j) acc[j] += sv * Vs[j2][m0+j];
  }
  float zi = den[row];
  f16* dst = O + ((size_t)(b*SEQ + ch*CHUNK + row))*DM + h*64 + m0;
#pragma unroll
  for (int j = 0; j < 8; ++j) dst[j] = (f16)(acc[j] * zi);
}

// ---------------- residual + split-K reduce + bias + layernorm ----------------
// v = x[t] + sum_{s<S} P[s][t] + bias  (P/bias null -> plain LN of x)
__global__ __launch_bounds__(256) void resid_ln_red(
    const float* __restrict__ x, const float* __restrict__ P, int S,
    const float* __restrict__ bias,
    const float* __restrict__ g, const float* __restrict__ bb,
    float* __restrict__ out, f16* __restrict__ out16) {
  int t = blockIdx.x;
  int tid = threadIdx.x;
  __shared__ float red[256];
  const float* xb = x + (size_t)t*DM;
  float v0 = xb[tid];
  float v1 = xb[tid+256];
  if (P) {
    for (int s = 0; s < S; ++s) {
      const float* Ps = P + (size_t)s*TOK*DM + (size_t)t*DM;
      v0 += Ps[tid];
      v1 += Ps[tid+256];
    }
    v0 += bias[tid];
    v1 += bias[tid+256];
  }
  red[tid] = v0 + v1;
  __syncthreads();
  for (int o = 128; o > 0; o >>= 1) {
    if (tid < o) red[tid] += red[tid+o];
    __syncthreads();
  }
  float mean = red[0] * (1.0f/512.0f);
  __syncthreads();
  float d0 = v0 - mean, d1 = v1 - mean;
  red[tid] = d0*d0 + d1*d1;
  __syncthreads();
  for (int o = 128; o > 0; o >>= 1) {
    if (tid < o) red[tid] += red[tid+o];
    __syncthreads();
  }
  float rs = rsqrtf(red[0] * (1.0f/512.0f) + 1e-5f);
  float r0 = d0*rs*g[tid]     + bb[tid];
  float r1 = d1*rs*g[tid+256] + bb[tid+256];
  out[(size_t)t*DM + tid]     = r0;
  out[(size_t)t*DM + tid+256] = r1;
  if (out16) {
    out16[(size_t)t*DM + tid]     = (f16)r0;
    out16[(size_t)t*DM + tid+256] = (f16)r1;
  }
}

// ---------------- collapsed output heads (parallel) ----------------
struct HeadPtrs {
  const float* pw[6]; const float* pb[6];
  const float* vw[6]; const float* vb[6];
};

__global__ __launch_bounds__(64) void head_u_par(HeadPtrs hp, float* __restrict__ U,
                                                 float* __restrict__ Cc) {
  const int vsz[6] = {56, 135, 18, 87, 18, 25};
  const int off[6] = {0, 56, 191, 209, 296, 314};
  int d = blockIdx.x;          // 0..511 -> U[d]; 512 -> Cc
  int tid = threadIdx.x;
  float acc = 0.0f;
  for (int jj = tid; jj < 339; jj += 64) {
    int i;
    if (jj < 191) i = (jj < 56) ? 0 : 1;
    else if (jj < 296) i = (jj < 209) ? 2 : 3;
    else i = (jj < 314) ? 4 : 5;
    int j = jj - off[i];
    float wv = (d < 512) ? hp.pw[i][(size_t)d * vsz[i] + j] : hp.pb[i][j];
    acc += wv * hp.vw[i][j];
  }
#pragma unroll
  for (int s = 32; s > 0; s >>= 1) acc += __shfl_down(acc, s);
  if (tid == 0) {
    if (d < 512) U[d] = acc;
    else {
      for (int i = 0; i < 6; ++i) acc += hp.vb[i][0];
      Cc[0] = acc;
    }
  }
}

__global__ __launch_bounds__(512) void final_out(
    const float* __restrict__ hf, const float* __restrict__ U,
    const float* __restrict__ Cc, float* __restrict__ out) {
  int b = blockIdx.x;
  int d = threadIdx.x;
  __shared__ float red[512];
  float cs = 0;
  const float* hb = hf + (size_t)b*SEQ*DM + d;
  for (int s = 0; s < SEQ; ++s) cs += hb[(size_t)s*DM];
  red[d] = cs * U[d];
  __syncthreads();
  for (int o = 256; o > 0; o >>= 1) {
    if (d < o) red[d] += red[d+o];
    __syncthreads();
  }
  if (d == 0) out[b] = (red[0] * (1.0f/512.0f) + Cc[0]) * (1.0f/6.0f);
}

// ---------------- launch ----------------
extern "C" void kernel_launch(void* const* d_in, const int* in_sizes, int n_in,
                              void* d_out, int out_size, void* d_ws, size_t ws_size,
                              hipStream_t stream) {
  const int*   x    = (const int*)d_in[0];
  const float* T0   = (const float*)d_in[1];
  const float* T1   = (const float*)d_in[2];
  const float* T2   = (const float*)d_in[3];
  const float* T3   = (const float*)d_in[4];
  const float* T4   = (const float*)d_in[5];
  const float* T5   = (const float*)d_in[6];
  const float* in_w = (const float*)d_in[7];
  const float* in_b = (const float*)d_in[8];
  const float* Wq   = (const float*)d_in[9];
  const float* Wk   = (const float*)d_in[10];
  const float* Wv   = (const float*)d_in[11];
  const float* Wo   = (const float*)d_in[12];
  const float* W1   = (const float*)d_in[13];
  const float* W2   = (const float*)d_in[14];
  const float* bq   = (const float*)d_in[15];
  const float* bk   = (const float*)d_in[16];
  const float* bv   = (const float*)d_in[17];
  const float* bo   = (const float*)d_in[18];
  const float* bf1  = (const float*)d_in[19];
  const float* bf2  = (const float*)d_in[20];
  const float* b1n  = (const float*)d_in[21];
  const float* b2n  = (const float*)d_in[22];
  const float* g1   = (const float*)d_in[23];
  const float* g2   = (const float*)d_in[24];
  const float* gf   = (const float*)d_in[25];
  const float* bfn  = (const float*)d_in[26];
  HeadPtrs hp;
  for (int i = 0; i < 6; ++i) {
    hp.pw[i] = (const float*)d_in[27 + i*4];
    hp.pb[i] = (const float*)d_in[28 + i*4];
    hp.vw[i] = (const float*)d_in[29 + i*4];
    hp.vb[i] = (const float*)d_in[30 + i*4];
  }

  float* ws   = (float*)d_ws;
  float* h    = ws;                 // 1024*512 fp32
  float* q    = h    + 524288;
  float* k    = q    + 524288;
  float* v    = k    + 524288;
  float* h2   = v    + 524288;
  float* Pa   = h2   + 524288;      // 2 * 1024*512 (Wo split-K partials)
  float* Pb   = Pa   + 1048576;     // 4 * 1024*512 (ff2 split-K partials)
  float* kvst = Pb   + 2097152;     // 16*16*64*64
  float* ksum = kvst + 1048576;     // 16*16*64
  float* U    = ksum + 16384;
  float* Cc   = U    + 512;
  f16* E16    = (f16*)(Cc + 16);    // 1024*1216
  f16* hf16   = E16   + 1245184;    // 1024*512
  f16* h2f16  = hf16  + 524288;
  f16* attn16 = h2f16 + 524288;
  f16* ff16   = attn16+ 524288;     // 1024*2048
  f16* in_wt  = ff16  + 2097152;    // 512*1216
  f16* qkvw   = in_wt + 623616;     // 12*1536*512
  f16* wot    = qkvw  + 9437184;    // 12*512*512
  f16* w1t    = wot   + 3145728;    // 12*2048*512
  f16* w2t    = w1t   + 12582912;   // 12*512*2048

  // weight conversion
  transp_convert<<<dim3(38,16,1),  256, 0, stream>>>(in_w, in_wt, 1216, 512, 0, 0);
  transp_convert_qkvo<<<dim3(16,16,48), 256, 0, stream>>>(Wq, Wk, Wv, Wo, qkvw, wot);
  transp_convert<<<dim3(16,64,12), 256, 0, stream>>>(W1, w1t,  512, 2048, 1048576, 1048576);
  transp_convert<<<dim3(64,16,12), 256, 0, stream>>>(W2, w2t, 2048,  512, 1048576, 1048576);

  embed_gather<<<TOK, 256, 0, stream>>>(x, T0, T1, T2, T3, T4, T5, E16);
  // input GEMM + bias + positional encoding, dual fp32/f16 out
  mfma_gemm<3><<<dim3(16,8), 256, 0, stream>>>(E16, in_wt, in_b, nullptr, nullptr,
                                               h, (float*)hf16, nullptr, TOK, 1216, 512);

  for (int l = 0; l < 12; ++l) {
    mfma_gemm<2><<<dim3(16,24), 256, 0, stream>>>(hf16, qkvw + (size_t)l*786432,
        bq + l*512, bk + l*512, bv + l*512, q, k, v, TOK, 512, 1536);
    attn_chunk_sums<<<dim3(NCH,16), 256, 0, stream>>>(k, v, kvst, ksum);
    attn_scan_par<<<dim3(17,16), 256, 0, stream>>>(kvst, ksum);
    attn_chunk_out<<<dim3(NCH,16), 256, 0, stream>>>(q, k, v, kvst, ksum, attn16);
    // Wo GEMM, split-K=2 -> Pa
    mfma_gemm_sk<<<dim3(16,8,2), 256, 0, stream>>>(attn16, wot + (size_t)l*262144,
        Pa, TOK, 512, 512, 256);
    resid_ln_red<<<TOK, 256, 0, stream>>>(h, Pa, 2, bo + l*512,
        g1 + l*512, b1n + l*512, h2, h2f16);
    mfma_gemm<1><<<dim3(16,32), 256, 0, stream>>>(h2f16, w1t + (size_t)l*1048576,
        bf1 + l*2048, nullptr, nullptr, (float*)ff16, nullptr, nullptr, TOK, 512, 2048);
    // ff2 GEMM, split-K=4 -> Pb
    mfma_gemm_sk<<<dim3(16,8,4), 256, 0, stream>>>(ff16, w2t + (size_t)l*1048576,
        Pb, TOK, 2048, 512, 512);
    resid_ln_red<<<TOK, 256, 0, stream>>>(h2, Pb, 4, bf2 + l*512,
        g2 + l*512, b2n + l*512, h, hf16);
  }

  resid_ln_red<<<TOK, 256, 0, stream>>>(h, nullptr, 0, nullptr, gf, bfn, h2, nullptr);
  head_u_par<<<513, 64, 0, stream>>>(hp, U, Cc);
  final_out<<<NB, 512, 0, stream>>>(h2, U, Cc, (float*)d_out);
}